// Round 1
// baseline (107.414 us; speedup 1.0000x reference)
//
#include <hip/hip_runtime.h>
#include <hip/hip_bf16.h>

// SeqChamferLoss: B=4, C=3, T=16, N=2048, fp32 in, scalar fp32 out.
// loss = mean over (b,t) of [ sum_m min_n ||x_n - y_m||^2  +  sum_n min_m ||x_n - y_m||^2 ]
// with x = gts, y = preds (points along N, coords along C; planes are [B,C,T,N]).

#define BV 4
#define CV 3
#define TV 16
#define NV 2048
#define PS (TV * NV)      // plane stride between consecutive c for fixed (b,t): T*N
#define THREADS 256
#define QPT 2             // queries per thread -> 512 queries per block
#define QCHUNK 4          // query chunks per (bt,dir): 4*512 = 2048

__global__ __launch_bounds__(THREADS)
void chamfer_kernel(const float* __restrict__ preds,
                    const float* __restrict__ gts,
                    float* __restrict__ out)
{
    // block decode: blk = ((bt*2 + dir)*QCHUNK + qc)
    int blk = blockIdx.x;
    int qc  = blk & (QCHUNK - 1);
    int dir = (blk >> 2) & 1;
    int bt  = blk >> 3;               // 0..63
    int b   = bt >> 4;                // T = 16
    int t   = bt & (TV - 1);

    // dir 0: queries = preds (y), refs = gts (x)   -> loss_1 terms
    // dir 1: queries = gts  (x), refs = preds (y)  -> loss_2 terms
    const float* qbase = dir ? gts   : preds;
    const float* rbase = dir ? preds : gts;

    // offset of plane c=0 for this (b,t): ((b*C + 0)*T + t)*N
    const size_t off = ((size_t)b * CV * TV + t) * (size_t)NV;
    const float* q0 = qbase + off;
    const float* r0 = rbase + off;

    // stage all refs, packed as (-2x, -2y, -2z, ||x||^2)
    __shared__ float4 refs[NV];       // 32 KB
    for (int i = threadIdx.x; i < NV; i += THREADS) {
        float x0 = r0[i];
        float x1 = r0[PS + i];
        float x2 = r0[2 * PS + i];
        float r  = fmaf(x0, x0, fmaf(x1, x1, x2 * x2));
        refs[i]  = make_float4(-2.0f * x0, -2.0f * x1, -2.0f * x2, r);
    }
    __syncthreads();

    // load this thread's queries
    float qx[QPT], qy[QPT], qz[QPT], rq[QPT], acc[QPT];
    const int m0 = qc * (THREADS * QPT) + threadIdx.x;
#pragma unroll
    for (int k = 0; k < QPT; ++k) {
        int m = m0 + k * THREADS;
        qx[k] = q0[m];
        qy[k] = q0[PS + m];
        qz[k] = q0[2 * PS + m];
        rq[k] = fmaf(qx[k], qx[k], fmaf(qy[k], qy[k], qz[k] * qz[k]));
        acc[k] = 3.4e38f;
    }

    // main loop: min over all refs (broadcast LDS reads)
#pragma unroll 8
    for (int n = 0; n < NV; ++n) {
        float4 r = refs[n];
#pragma unroll
        for (int k = 0; k < QPT; ++k) {
            float d = fmaf(r.x, qx[k], r.w);
            d = fmaf(r.y, qy[k], d);
            d = fmaf(r.z, qz[k], d);
            acc[k] = fminf(acc[k], d);
        }
    }

    // per-thread sum of (min + ||q||^2)
    float s = 0.0f;
#pragma unroll
    for (int k = 0; k < QPT; ++k) s += acc[k] + rq[k];

    // block reduction: wave shuffle then LDS across 4 waves
#pragma unroll
    for (int o = 32; o > 0; o >>= 1) s += __shfl_down(s, o, 64);

    __shared__ float red[THREADS / 64];
    int wid  = threadIdx.x >> 6;
    int lane = threadIdx.x & 63;
    if (lane == 0) red[wid] = s;
    __syncthreads();
    if (threadIdx.x == 0) {
        float tot = red[0] + red[1] + red[2] + red[3];
        atomicAdd(out, tot * (1.0f / (BV * TV)));
    }
}

extern "C" void kernel_launch(void* const* d_in, const int* in_sizes, int n_in,
                              void* d_out, int out_size, void* d_ws, size_t ws_size,
                              hipStream_t stream) {
    const float* preds = (const float*)d_in[0];
    const float* gts   = (const float*)d_in[1];
    float* out = (float*)d_out;

    // zero the scalar accumulator (harness poisons d_out with 0xAA)
    hipMemsetAsync(out, 0, sizeof(float), stream);

    const int nblocks = BV * TV * 2 * QCHUNK;   // 64 * 2 * 4 = 512
    chamfer_kernel<<<nblocks, THREADS, 0, stream>>>(preds, gts, out);
}